// Round 1
// baseline (918.723 us; speedup 1.0000x reference)
//
#include <hip/hip_runtime.h>
#include <hip/hip_bf16.h>
#include <stdint.h>
#include <stddef.h>

typedef __bf16 bf16_t;
typedef __attribute__((ext_vector_type(8))) __bf16 bf16x8;
typedef __attribute__((ext_vector_type(4))) __bf16 bf16x4;
typedef __attribute__((ext_vector_type(4))) float f32x4;

#define HDIM 1024
#define MSLOTS 16384
#define NROWS 8192  // B*S

__device__ __forceinline__ void load16_lds(const void* g, void* l) {
  __builtin_amdgcn_global_load_lds((const __attribute__((address_space(1))) void*)g,
                                   (__attribute__((address_space(3))) void*)l, 16, 0, 0);
}

// zero the compacted mask
__global__ void init_compact(int* __restrict__ cmask) {
  int i = blockIdx.x * blockDim.x + threadIdx.x;
  if (i < MSLOTS) cmask[i] = 0;
}

// Single-block deterministic compaction: posmap[pos] = slot for used slots (sorted),
// cmask[pos] = 1, smalls[0] = count, smalls[1] = count padded to mult of 512.
__global__ void compact_scan(const int* __restrict__ usage, int* __restrict__ posmap,
                             int* __restrict__ cmask, int* __restrict__ smalls) {
  __shared__ int wtot[16], wbase[16];
  const int t = threadIdx.x;          // 0..1023
  const int lane = t & 63, wid = t >> 6;
  const int base = t * 16;
  unsigned mask = 0;
  int c = 0;
  #pragma unroll
  for (int i = 0; i < 16; ++i) {
    if (usage[base + i] > 0) { mask |= (1u << i); ++c; }
  }
  int inc = c;
  #pragma unroll
  for (int d = 1; d < 64; d <<= 1) {
    int n = __shfl_up(inc, d);
    if (lane >= d) inc += n;
  }
  if (lane == 63) wtot[wid] = inc;
  __syncthreads();
  if (t == 0) {
    int acc = 0;
    #pragma unroll
    for (int w = 0; w < 16; ++w) { wbase[w] = acc; acc += wtot[w]; }
    smalls[0] = acc;
    smalls[1] = ((acc + 511) >> 9) << 9;
  }
  __syncthreads();
  int pos = wbase[wid] + inc - c;
  #pragma unroll
  for (int i = 0; i < 16; ++i) {
    if ((mask >> i) & 1u) {
      posmap[pos] = base + i;
      cmask[pos] = 1;
      ++pos;
    }
  }
}

// fp32 -> bf16 convert, 8 elems/thread
__global__ void cvt_f32_bf16(const float* __restrict__ X, bf16_t* __restrict__ Y, int n8) {
  int i = blockIdx.x * blockDim.x + threadIdx.x;
  if (i >= n8) return;
  float4 a = ((const float4*)X)[2 * i];
  float4 b = ((const float4*)X)[2 * i + 1];
  bf16x8 o;
  o[0] = (bf16_t)a.x; o[1] = (bf16_t)a.y; o[2] = (bf16_t)a.z; o[3] = (bf16_t)a.w;
  o[4] = (bf16_t)b.x; o[5] = (bf16_t)b.y; o[6] = (bf16_t)b.z; o[7] = (bf16_t)b.w;
  ((bf16x8*)Y)[i] = o;
}

// L2-normalize rows of length 1024, fp32 in -> bf16 out (for q)
__global__ void normalize_rows(const float* __restrict__ X, bf16_t* __restrict__ Y) {
  __shared__ float part[4];
  const int t = threadIdx.x;
  const size_t row = blockIdx.x;
  float4 v = ((const float4*)(X + row * 1024))[t];
  float s = v.x * v.x + v.y * v.y + v.z * v.z + v.w * v.w;
  #pragma unroll
  for (int m = 32; m >= 1; m >>= 1) s += __shfl_xor(s, m);
  if ((t & 63) == 0) part[t >> 6] = s;
  __syncthreads();
  float tot = part[0] + part[1] + part[2] + part[3];
  float r = rsqrtf(tot + 1e-6f);
  bf16x4 o;
  o[0] = (bf16_t)(v.x * r); o[1] = (bf16_t)(v.y * r);
  o[2] = (bf16_t)(v.z * r); o[3] = (bf16_t)(v.w * r);
  *(bf16x4*)&Y[row * 1024 + t * 4] = o;
}

// cmkn[p] = normalize(mk[posmap[p]]) for p<cnt; zeros for cnt<=p<mpad. No atomics.
__global__ void normalize_gather(const float* __restrict__ mk, const int* __restrict__ posmap,
                                 const int* __restrict__ smalls, bf16_t* __restrict__ cmkn) {
  __shared__ float part[4];
  const int p = blockIdx.x;
  const int cnt = smalls[0], mpad = smalls[1];
  if (p >= mpad) return;
  const int t = threadIdx.x;
  if (p >= cnt) {
    bf16x4 z;
    z[0] = z[1] = z[2] = z[3] = (bf16_t)0.f;
    *(bf16x4*)&cmkn[(size_t)p * 1024 + t * 4] = z;
    return;
  }
  const int slot = posmap[p];
  float4 v = ((const float4*)(mk + (size_t)slot * 1024))[t];
  float s = v.x * v.x + v.y * v.y + v.z * v.z + v.w * v.w;
  #pragma unroll
  for (int m = 32; m >= 1; m >>= 1) s += __shfl_xor(s, m);
  if ((t & 63) == 0) part[t >> 6] = s;
  __syncthreads();
  float tot = part[0] + part[1] + part[2] + part[3];
  float r = rsqrtf(tot + 1e-6f);
  bf16x4 o;
  o[0] = (bf16_t)(v.x * r); o[1] = (bf16_t)(v.y * r);
  o[2] = (bf16_t)(v.z * r); o[3] = (bf16_t)(v.w * r);
  *(bf16x4*)&cmkn[(size_t)p * 1024 + t * 4] = o;
}

// cVt[h][pos] = pos<cnt ? mv[posmap[pos]][h] : 0, for pos < mpad
__global__ void transpose_gather(const float* __restrict__ mv, const int* __restrict__ posmap,
                                 const int* __restrict__ smalls, bf16_t* __restrict__ cVt) {
  __shared__ float tile[32][33];
  const int cnt = smalls[0], mpad = smalls[1];
  const int p0 = blockIdx.y * 32;
  if (p0 >= mpad) return;
  const int tx = threadIdx.x & 31, ty = threadIdx.x >> 5;  // 32 x 8
  const int h0 = blockIdx.x * 32;
  #pragma unroll
  for (int j = 0; j < 32; j += 8) {
    const int pos = p0 + ty + j;
    float val = 0.f;
    if (pos < cnt) val = mv[(size_t)posmap[pos] * 1024 + h0 + tx];
    tile[ty + j][tx] = val;
  }
  __syncthreads();
  #pragma unroll
  for (int j = 0; j < 32; j += 8)
    cVt[(size_t)(h0 + ty + j) * MSLOTS + p0 + tx] = (bf16_t)tile[tx][ty + j];
}

__global__ void zero_f32(float* __restrict__ p, int n4) {
  int i = blockIdx.x * blockDim.x + threadIdx.x;
  if (i < n4) ((float4*)p)[i] = (float4){0.f, 0.f, 0.f, 0.f};
}

// out = retrf * (1/den[row]) -> bf16 (atomic split-K mode)
__global__ void scale_cvt(const float* __restrict__ retrf, const float* __restrict__ den,
                          bf16_t* __restrict__ out, int n4) {
  int i = blockIdx.x * blockDim.x + threadIdx.x;
  if (i >= n4) return;
  float4 s = ((const float4*)retrf)[i];
  const int row = (i * 4) >> 10;  // HDIM=1024
  const float r = 1.0f / den[row];
  bf16x4 o;
  o[0] = (bf16_t)(s.x * r); o[1] = (bf16_t)(s.y * r);
  o[2] = (bf16_t)(s.z * r); o[3] = (bf16_t)(s.w * r);
  ((bf16x4*)out)[i] = o;
}

// sum ks fp32 partial slabs, scale by 1/den[row], store bf16 (partial split-K mode)
__global__ void reduce_scale(const float* __restrict__ part, size_t partStride, int ks,
                             const float* __restrict__ den, bf16_t* __restrict__ out, int n4) {
  int i = blockIdx.x * blockDim.x + threadIdx.x;
  if (i >= n4) return;
  float4 s = ((const float4*)part)[i];
  for (int k = 1; k < ks; ++k) {
    float4 t = ((const float4*)(part + (size_t)k * partStride))[i];
    s.x += t.x; s.y += t.y; s.z += t.z; s.w += t.w;
  }
  const int row = (i * 4) >> 10;  // HDIM=1024
  const float r = 1.0f / den[row];
  bf16x4 o;
  o[0] = (bf16_t)(s.x * r); o[1] = (bf16_t)(s.y * r);
  o[2] = (bf16_t)(s.z * r); o[3] = (bf16_t)(s.w * r);
  ((bf16x4*)out)[i] = o;
}

// ---------------------------------------------------------------------------
// 256x256-tile BK=32 GEMM with a 4-deep LDS ring + counted vmcnt (T3+T4).
// C = A * Bt^T. A:[rows,ldk], Bt:[N,ldk] row-major, 8 waves (512 thr), each
// wave owns a 128x64 output sub-tile (2M x 4N wave grid).
//
// Schedule per K-tile t (32 K):
//   stage tile t+3 into ring slot (t+3)&3   (4 x global_load_lds / thread)
//   s_waitcnt vmcnt(12)  -> tile t's 4 loads landed, t+1..t+3 stay in flight
//   s_barrier            -> all waves agree tile t is in LDS
//   ds_read 12 x b128; 32 x mfma_16x16x32_bf16 (setprio around the cluster)
//   s_barrier            -> nobody still reads slot t&3 before it is re-staged
// Stages lead compute by 3 tiles (~3x tile-time > 900cy HBM latency), so the
// P-stream (92 MB, L2-missing) no longer exposes its latency each K-step —
// that was gemm_bt<3>'s 25.7% MfmaUtil. BK=32 keeps LDS rows at 64 B stride:
// the b128 fragment read pattern spreads 8 lanes/16B-quad evenly across all
// 32 banks, so no XOR swizzle is needed and global_load_lds keeps a linear dest.
//
// EPI 1: outb = cmask[col] ? exp(10*acc) : 0 (bf16) + atomic row-sums into den
// EPI 3: split-K over K=mpad: atomicAdd(outf, acc)
// EPI 4: split-K over K=mpad: outf[z-slab] = acc
template <int EPI>
__global__ __launch_bounds__(512, 2)
void gemm256(const bf16_t* __restrict__ A, const bf16_t* __restrict__ Bt,
             int ldk, int kLenIn, int ldc,
             const float* __restrict__ bias,
             const int* __restrict__ cmask,
             float* __restrict__ den,
             float* __restrict__ outf, bf16_t* __restrict__ outb,
             const int* __restrict__ smalls, int ks, size_t partStride) {
  __shared__ bf16_t lA[4][256 * 32];  // 64 KiB
  __shared__ bf16_t lB[4][256 * 32];  // 64 KiB
  const int tid = threadIdx.x;
  const int lane = tid & 63;
  const int wave = tid >> 6;
  const int wr = wave >> 2;  // 0..1  M half
  const int wc = wave & 3;   // 0..3  N quarter
  const int lr = lane & 15;
  const int lq = lane >> 4;

  int bx = blockIdx.x, by = blockIdx.y, bz = blockIdx.z;
  {
    const unsigned nx = gridDim.x, ny = gridDim.y;
    if ((ny & 7u) == 0u) {  // XCD-aware y-inner swizzle (bijective: exact /8)
      unsigned lin = blockIdx.x + nx * (blockIdx.y + ny * blockIdx.z);
      unsigned ylow = lin & 7u;
      lin >>= 3;
      const unsigned nyh = ny >> 3;
      unsigned yhigh = lin % nyh;
      lin /= nyh;
      bx = lin % nx;
      bz = lin / nx;
      by = ylow + 8u * yhigh;
    }
  }

  int kLen = kLenIn;
  int kstart = 0;
  if (EPI == 1) {
    if (bx * 256 >= smalls[1]) return;  // compacted N bound (block-uniform)
  }
  if (EPI == 3 || EPI == 4) {
    kLen = smalls[1] / ks;  // mpad % 512 == 0 -> kLen % 32 == 0 for ks in {4,8,16}
    kstart = bz * kLen;
  }
  const int nt = kLen >> 5;

  // Stage addressing: 256 rows x 64 B per operand tile = 1024 x 16 B chunks;
  // thread t handles chunks t (rows 0..127) and t+512 (rows 128..255).
  const int srow = tid >> 2;         // 0..127
  const int scol = (tid & 3) * 8;    // elems
  const bf16_t* pA0 = A + (size_t)(by * 256 + srow) * ldk + kstart + scol;
  const bf16_t* pA1 = pA0 + (size_t)128 * ldk;
  const bf16_t* pB0 = Bt + (size_t)(bx * 256 + srow) * ldk + kstart + scol;
  const bf16_t* pB1 = pB0 + (size_t)128 * ldk;

  f32x4 acc[8][4];
  #pragma unroll
  for (int m = 0; m < 8; ++m)
    #pragma unroll
    for (int n = 0; n < 4; ++n) acc[m][n] = (f32x4){0.f, 0.f, 0.f, 0.f};

#define STAGE(tt)                                              \
  do {                                                         \
    const int _b = (tt) & 3;                                   \
    const size_t _ko = (size_t)(tt) * 32;                      \
    load16_lds(pA0 + _ko, &lA[_b][tid * 8]);                   \
    load16_lds(pA1 + _ko, &lA[_b][4096 + tid * 8]);            \
    load16_lds(pB0 + _ko, &lB[_b][tid * 8]);                   \
    load16_lds(pB1 + _ko, &lB[_b][4096 + tid * 8]);            \
  } while (0)

  if (nt > 0) STAGE(0);
  if (nt > 1) STAGE(1);
  if (nt > 2) STAGE(2);

  for (int t = 0; t < nt; ++t) {
    if (t + 3 < nt) STAGE(t + 3);
    const int rem = nt - 1 - t;  // tiles staged beyond t still wanted in flight
    if (rem >= 3)      asm volatile("s_waitcnt vmcnt(12)" ::: "memory");
    else if (rem == 2) asm volatile("s_waitcnt vmcnt(8)" ::: "memory");
    else if (rem == 1) asm volatile("s_waitcnt vmcnt(4)" ::: "memory");
    else               asm volatile("s_waitcnt vmcnt(0)" ::: "memory");
    __builtin_amdgcn_s_barrier();
    __builtin_amdgcn_sched_barrier(0);
    const int b = t & 3;
    const bf16_t* bAp = &lA[b][0];
    const bf16_t* bBp = &lB[b][0];
    bf16x8 bfr[4];
    #pragma unroll
    for (int n = 0; n < 4; ++n)
      bfr[n] = *(const bf16x8*)&bBp[(wc * 64 + n * 16 + lr) * 32 + lq * 8];
    __builtin_amdgcn_s_setprio(1);
    #pragma unroll
    for (int m = 0; m < 8; ++m) {
      bf16x8 af = *(const bf16x8*)&bAp[(wr * 128 + m * 16 + lr) * 32 + lq * 8];
      #pragma unroll
      for (int n = 0; n < 4; ++n)
        acc[m][n] = __builtin_amdgcn_mfma_f32_16x16x32_bf16(af, bfr[n], acc[m][n], 0, 0, 0);
    }
    __builtin_amdgcn_s_setprio(0);
    __builtin_amdgcn_sched_barrier(0);
    __builtin_amdgcn_s_barrier();
    __builtin_amdgcn_sched_barrier(0);
  }
#undef STAGE

  // C/D layout (m89-verified): col = lane&15, row = (lane>>4)*4 + r
  const int colBase = bx * 256 + wc * 64 + lr;
  const int rowBase = by * 256 + wr * 128 + lq * 4;

  if (EPI == 1) {
    bool ok[4];
    #pragma unroll
    for (int n = 0; n < 4; ++n) ok[n] = cmask[colBase + n * 16] > 0;
    #pragma unroll
    for (int m = 0; m < 8; ++m) {
      #pragma unroll
      for (int r = 0; r < 4; ++r) {
        const int row = rowBase + m * 16 + r;
        float s = 0.f;
        #pragma unroll
        for (int n = 0; n < 4; ++n) {
          float e = ok[n] ? exp2f(acc[m][n][r] * 14.426950408889634f) : 0.f;
          s += e;
          outb[(size_t)row * ldc + colBase + n * 16] = (bf16_t)e;
        }
        // reduce over the 16-lane col group, one atomic per row per wave
        s += __shfl_xor(s, 1);
        s += __shfl_xor(s, 2);
        s += __shfl_xor(s, 4);
        s += __shfl_xor(s, 8);
        if (lr == 0) atomicAdd(&den[row], s);
      }
    }
  }
  if (EPI == 3 || EPI == 4) {
    if (EPI == 4) outf += (size_t)bz * partStride;
    #pragma unroll
    for (int m = 0; m < 8; ++m)
      #pragma unroll
      for (int n = 0; n < 4; ++n)
        #pragma unroll
        for (int r = 0; r < 4; ++r) {
          const size_t idx = (size_t)(rowBase + m * 16 + r) * ldc + colBase + n * 16;
          if (EPI == 3) atomicAdd(&outf[idx], acc[m][n][r]);
          else outf[idx] = acc[m][n][r];
        }
  }
}

// m97-style 128x128 bf16 GEMM (kept for the two HxH projections: 512 blocks
// fill all 256 CUs, and their operands are L2-resident so the drain-style
// loop is adequate). C = A * Bt^T, EPI 0: outf = acc + bias[col].
template <int EPI>
__global__ void gemm_bt(const bf16_t* __restrict__ A, const bf16_t* __restrict__ Bt,
                        int ldk, int kLenIn, int ldc,
                        const float* __restrict__ bias,
                        const int* __restrict__ cmask,
                        float* __restrict__ den,
                        float* __restrict__ outf, bf16_t* __restrict__ outb,
                        const int* __restrict__ smalls, int ks, size_t partStride) {
  __shared__ bf16_t lA[128 * 32];
  __shared__ bf16_t lB[128 * 32];
  const int t = threadIdx.x;
  const int lane = t & 63;
  const int wave = t >> 6;
  const int wm = (wave >> 1) << 6;
  const int wn = (wave & 1) << 6;
  const int lr = lane & 15;
  const int lq = lane >> 4;

  int bx = blockIdx.x, by = blockIdx.y, bz = blockIdx.z;
  {
    const unsigned nx = gridDim.x, ny = gridDim.y;
    if ((ny & 7u) == 0u) {
      unsigned lin = blockIdx.x + nx * (blockIdx.y + ny * blockIdx.z);
      unsigned ylow = lin & 7u;
      lin >>= 3;
      const unsigned nyh = ny >> 3;
      unsigned yhigh = lin % nyh;
      lin /= nyh;
      bx = lin % nx;
      bz = lin / nx;
      by = ylow + 8u * yhigh;
    }
  }

  int kLen = kLenIn;
  int kstart = 0;

  const int r0 = t >> 2;
  const int c0 = (t & 3) * 8;
  const bf16_t* pA0 = A + (size_t)(by * 128 + r0) * ldk + kstart + c0;
  const bf16_t* pA1 = pA0 + (size_t)64 * ldk;
  const bf16_t* pB0 = Bt + (size_t)(bx * 128 + r0) * ldk + kstart + c0;
  const bf16_t* pB1 = pB0 + (size_t)64 * ldk;

  f32x4 acc[4][4];
  #pragma unroll
  for (int i = 0; i < 4; ++i)
    #pragma unroll
    for (int j = 0; j < 4; ++j) acc[i][j] = (f32x4){0.f, 0.f, 0.f, 0.f};

  for (int k0 = 0; k0 < kLen; k0 += 32) {
    __syncthreads();
    load16_lds(pA0, &lA[t * 8]);
    load16_lds(pA1, &lA[2048 + t * 8]);
    load16_lds(pB0, &lB[t * 8]);
    load16_lds(pB1, &lB[2048 + t * 8]);
    pA0 += 32; pA1 += 32; pB0 += 32; pB1 += 32;
    __syncthreads();
    bf16x8 af[4], bfr[4];
    #pragma unroll
    for (int i = 0; i < 4; ++i)
      af[i] = *(const bf16x8*)&lA[(wm + i * 16 + lr) * 32 + lq * 8];
    #pragma unroll
    for (int j = 0; j < 4; ++j)
      bfr[j] = *(const bf16x8*)&lB[(wn + j * 16 + lr) * 32 + lq * 8];
    #pragma unroll
    for (int i = 0; i < 4; ++i)
      #pragma unroll
      for (int j = 0; j < 4; ++j)
        acc[i][j] = __builtin_amdgcn_mfma_f32_16x16x32_bf16(af[i], bfr[j], acc[i][j], 0, 0, 0);
  }

  const int colBase = bx * 128 + wn + lr;
  const int rowBase = by * 128 + wm + lq * 4;

  #pragma unroll
  for (int j = 0; j < 4; ++j) {
    const int col = colBase + j * 16;
    float bval = 0.f;
    if (EPI == 0) bval = bias[col];
    #pragma unroll
    for (int i = 0; i < 4; ++i) {
      const int row = rowBase + i * 16;
      #pragma unroll
      for (int r = 0; r < 4; ++r) {
        const size_t idx = (size_t)(row + r) * ldc + col;
        float v = acc[i][j][r];
        if (EPI == 0) outf[idx] = v + bval;
      }
    }
  }
}

extern "C" void kernel_launch(void* const* d_in, const int* in_sizes, int n_in,
                              void* d_out, int out_size, void* d_ws, size_t ws_size,
                              hipStream_t stream) {
  const float* hs = (const float*)d_in[0];
  const float* Wk = (const float*)d_in[1];
  const float* bk = (const float*)d_in[2];
  // d_in[3]=Wv, d_in[4]=bv are unused by the reference
  const float* Wo = (const float*)d_in[5];
  const float* bo = (const float*)d_in[6];
  const float* mk = (const float*)d_in[7];
  const float* mv = (const float*)d_in[8];
  const int* usage = (const int*)d_in[9];
  float* out = (float*)d_out;

  char* ws = (char*)d_ws;
  size_t off = 0;
  auto alloc = [&](size_t b) -> void* {
    void* p = ws + off;
    off += (b + 255) & ~(size_t)255;
    return p;
  };
  // Persistent buffers (live across the chunk loop)
  bf16_t* cmkn = (bf16_t*)alloc((size_t)MSLOTS * HDIM * 2);
  bf16_t* cVt = (bf16_t*)alloc((size_t)HDIM * MSLOTS * 2);
  bf16_t* qnb = (bf16_t*)alloc((size_t)NROWS * HDIM * 2);
  bf16_t* retrb = (bf16_t*)alloc((size_t)NROWS * HDIM * 2);
  bf16_t* Wob = (bf16_t*)alloc((size_t)HDIM * HDIM * 2);
  float* den = (float*)alloc((size_t)NROWS * 4);
  int* posmap = (int*)alloc((size_t)MSLOTS * 4);
  int* cmask = (int*)alloc((size_t)MSLOTS * 4);
  int* smalls = (int*)alloc(256 * 4);
  const size_t fixed = off;

  // Overlay region: phase A = [hsb][Wkb][qf] (dead after stage 1);
  // loop = [P chunk][retrf or partial slabs]. Ladder: prefer partial-slab split-K
  // (no atomic RMW), fall back to atomic accumulate when ws is tight.
  // All chunks are multiples of 256 (gemm256 tile height).
  int chunk = 256, ksplit = 4, partialMode = 0;
  {
    const int cc[8] = {4096, 4096, 2048, 2048, 1024, 1024, 512, 256};
    const int kk[8] = {4, 4, 8, 8, 8, 8, 16, 4};
    const int pp[8] = {1, 0, 1, 0, 1, 0, 0, 0};
    for (int ci = 0; ci < 8; ++ci) {
      size_t outBytes = pp[ci] ? (size_t)cc[ci] * HDIM * 4 * kk[ci] : (size_t)cc[ci] * HDIM * 4;
      size_t region = (size_t)cc[ci] * MSLOTS * 2 + outBytes;
      size_t phaseA = (size_t)NROWS * HDIM * 2 + (size_t)HDIM * HDIM * 2 +
                      (size_t)NROWS * HDIM * 4 + 1024;
      if (region < phaseA) region = phaseA;
      if (fixed + region <= ws_size) {
        chunk = cc[ci]; ksplit = kk[ci]; partialMode = pp[ci];
        break;
      }
    }
  }
  bf16_t* hsb = (bf16_t*)(ws + fixed);
  bf16_t* Wkb = (bf16_t*)(ws + fixed + (size_t)NROWS * HDIM * 2);
  float* qf = (float*)(ws + fixed + (size_t)NROWS * HDIM * 2 + (size_t)HDIM * HDIM * 2);
  bf16_t* P = (bf16_t*)(ws + fixed);
  float* retrf = (float*)(ws + fixed + (size_t)chunk * MSLOTS * 2);  // or slab base
  const size_t partStride = (size_t)chunk * HDIM;

  // ---- stage 0: compaction + dtype prep ----
  init_compact<<<MSLOTS / 256, 256, 0, stream>>>(cmask);
  compact_scan<<<1, 1024, 0, stream>>>(usage, posmap, cmask, smalls);
  cvt_f32_bf16<<<(NROWS * HDIM / 8 + 255) / 256, 256, 0, stream>>>(hs, hsb, NROWS * HDIM / 8);
  cvt_f32_bf16<<<(HDIM * HDIM / 8 + 255) / 256, 256, 0, stream>>>(Wk, Wkb, HDIM * HDIM / 8);
  cvt_f32_bf16<<<(HDIM * HDIM / 8 + 255) / 256, 256, 0, stream>>>(Wo, Wob, HDIM * HDIM / 8);
  normalize_gather<<<MSLOTS, 256, 0, stream>>>(mk, posmap, smalls, cmkn);
  transpose_gather<<<dim3(HDIM / 32, MSLOTS / 32), 256, 0, stream>>>(mv, posmap, smalls, cVt);

  // ---- stage 1: q = hs @ Wk^T + bk (fp32), then normalize -> qn bf16 ----
  gemm_bt<0><<<dim3(HDIM / 128, NROWS / 128), 256, 0, stream>>>(
      hsb, Wkb, HDIM, HDIM, HDIM, bk, nullptr, nullptr, qf, nullptr, smalls, 1, 0);
  normalize_rows<<<NROWS, 256, 0, stream>>>(qf, qnb);

  // ---- stage 2/3: P = exp(10 * qn@cmkn^T) masked (+row sums); retr = P@V / den ----
  for (int c = 0; c < NROWS; c += chunk) {
    zero_f32<<<(chunk / 4 + 255) / 256, 256, 0, stream>>>(den, chunk / 4);
    gemm256<1><<<dim3(MSLOTS / 256, chunk / 256), 512, 0, stream>>>(
        qnb + (size_t)c * HDIM, cmkn, HDIM, HDIM, MSLOTS, nullptr, cmask, den, nullptr, P,
        smalls, 1, 0);
    if (partialMode) {
      gemm256<4><<<dim3(HDIM / 256, chunk / 256, ksplit), 512, 0, stream>>>(
          P, cVt, MSLOTS, 0, HDIM, nullptr, nullptr, nullptr, retrf, nullptr, smalls, ksplit,
          partStride);
      reduce_scale<<<(chunk * HDIM / 4 + 255) / 256, 256, 0, stream>>>(
          retrf, partStride, ksplit, den, retrb + (size_t)c * HDIM, chunk * HDIM / 4);
    } else {
      zero_f32<<<(chunk * HDIM / 4 + 255) / 256, 256, 0, stream>>>(retrf, chunk * HDIM / 4);
      gemm256<3><<<dim3(HDIM / 256, chunk / 256, ksplit), 512, 0, stream>>>(
          P, cVt, MSLOTS, 0, HDIM, nullptr, nullptr, nullptr, retrf, nullptr, smalls, ksplit,
          0);
      scale_cvt<<<(chunk * HDIM / 4 + 255) / 256, 256, 0, stream>>>(
          retrf, den, retrb + (size_t)c * HDIM, chunk * HDIM / 4);
    }
  }

  // ---- stage 4: out = retrieved @ Wo^T + bo (fp32) ----
  gemm_bt<0><<<dim3(HDIM / 128, NROWS / 128), 256, 0, stream>>>(
      retrb, Wob, HDIM, HDIM, HDIM, bo, nullptr, nullptr, out, nullptr, smalls, 1, 0);
}

// Round 3
// 796.723 us; speedup vs baseline: 1.1531x; 1.1531x over previous
//
#include <hip/hip_runtime.h>
#include <hip/hip_bf16.h>
#include <stdint.h>
#include <stddef.h>

typedef __bf16 bf16_t;
typedef __attribute__((ext_vector_type(8))) __bf16 bf16x8;
typedef __attribute__((ext_vector_type(4))) __bf16 bf16x4;
typedef __attribute__((ext_vector_type(4))) float f32x4;

#define HDIM 1024
#define MSLOTS 16384
#define NROWS 8192  // B*S

__device__ __forceinline__ void load16_lds(const void* g, void* l) {
  __builtin_amdgcn_global_load_lds((const __attribute__((address_space(1))) void*)g,
                                   (__attribute__((address_space(3))) void*)l, 16, 0, 0);
}

// zero the compacted mask
__global__ void init_compact(int* __restrict__ cmask) {
  int i = blockIdx.x * blockDim.x + threadIdx.x;
  if (i < MSLOTS) cmask[i] = 0;
}

// Single-block deterministic compaction: posmap[pos] = slot for used slots (sorted),
// cmask[pos] = 1, smalls[0] = count, smalls[1] = count padded to mult of 512.
__global__ void compact_scan(const int* __restrict__ usage, int* __restrict__ posmap,
                             int* __restrict__ cmask, int* __restrict__ smalls) {
  __shared__ int wtot[16], wbase[16];
  const int t = threadIdx.x;          // 0..1023
  const int lane = t & 63, wid = t >> 6;
  const int base = t * 16;
  unsigned mask = 0;
  int c = 0;
  #pragma unroll
  for (int i = 0; i < 16; ++i) {
    if (usage[base + i] > 0) { mask |= (1u << i); ++c; }
  }
  int inc = c;
  #pragma unroll
  for (int d = 1; d < 64; d <<= 1) {
    int n = __shfl_up(inc, d);
    if (lane >= d) inc += n;
  }
  if (lane == 63) wtot[wid] = inc;
  __syncthreads();
  if (t == 0) {
    int acc = 0;
    #pragma unroll
    for (int w = 0; w < 16; ++w) { wbase[w] = acc; acc += wtot[w]; }
    smalls[0] = acc;
    smalls[1] = ((acc + 511) >> 9) << 9;
  }
  __syncthreads();
  int pos = wbase[wid] + inc - c;
  #pragma unroll
  for (int i = 0; i < 16; ++i) {
    if ((mask >> i) & 1u) {
      posmap[pos] = base + i;
      cmask[pos] = 1;
      ++pos;
    }
  }
}

// fp32 -> bf16 convert, 8 elems/thread
__global__ void cvt_f32_bf16(const float* __restrict__ X, bf16_t* __restrict__ Y, int n8) {
  int i = blockIdx.x * blockDim.x + threadIdx.x;
  if (i >= n8) return;
  float4 a = ((const float4*)X)[2 * i];
  float4 b = ((const float4*)X)[2 * i + 1];
  bf16x8 o;
  o[0] = (bf16_t)a.x; o[1] = (bf16_t)a.y; o[2] = (bf16_t)a.z; o[3] = (bf16_t)a.w;
  o[4] = (bf16_t)b.x; o[5] = (bf16_t)b.y; o[6] = (bf16_t)b.z; o[7] = (bf16_t)b.w;
  ((bf16x8*)Y)[i] = o;
}

// L2-normalize rows of length 1024, fp32 in -> bf16 out (for q)
__global__ void normalize_rows(const float* __restrict__ X, bf16_t* __restrict__ Y) {
  __shared__ float part[4];
  const int t = threadIdx.x;
  const size_t row = blockIdx.x;
  float4 v = ((const float4*)(X + row * 1024))[t];
  float s = v.x * v.x + v.y * v.y + v.z * v.z + v.w * v.w;
  #pragma unroll
  for (int m = 32; m >= 1; m >>= 1) s += __shfl_xor(s, m);
  if ((t & 63) == 0) part[t >> 6] = s;
  __syncthreads();
  float tot = part[0] + part[1] + part[2] + part[3];
  float r = rsqrtf(tot + 1e-6f);
  bf16x4 o;
  o[0] = (bf16_t)(v.x * r); o[1] = (bf16_t)(v.y * r);
  o[2] = (bf16_t)(v.z * r); o[3] = (bf16_t)(v.w * r);
  *(bf16x4*)&Y[row * 1024 + t * 4] = o;
}

// cmkn[p] = normalize(mk[posmap[p]]) for p<cnt; zeros for cnt<=p<mpad. No atomics.
__global__ void normalize_gather(const float* __restrict__ mk, const int* __restrict__ posmap,
                                 const int* __restrict__ smalls, bf16_t* __restrict__ cmkn) {
  __shared__ float part[4];
  const int p = blockIdx.x;
  const int cnt = smalls[0], mpad = smalls[1];
  if (p >= mpad) return;
  const int t = threadIdx.x;
  if (p >= cnt) {
    bf16x4 z;
    z[0] = z[1] = z[2] = z[3] = (bf16_t)0.f;
    *(bf16x4*)&cmkn[(size_t)p * 1024 + t * 4] = z;
    return;
  }
  const int slot = posmap[p];
  float4 v = ((const float4*)(mk + (size_t)slot * 1024))[t];
  float s = v.x * v.x + v.y * v.y + v.z * v.z + v.w * v.w;
  #pragma unroll
  for (int m = 32; m >= 1; m >>= 1) s += __shfl_xor(s, m);
  if ((t & 63) == 0) part[t >> 6] = s;
  __syncthreads();
  float tot = part[0] + part[1] + part[2] + part[3];
  float r = rsqrtf(tot + 1e-6f);
  bf16x4 o;
  o[0] = (bf16_t)(v.x * r); o[1] = (bf16_t)(v.y * r);
  o[2] = (bf16_t)(v.z * r); o[3] = (bf16_t)(v.w * r);
  *(bf16x4*)&cmkn[(size_t)p * 1024 + t * 4] = o;
}

// cVt[h][pos] = pos<cnt ? mv[posmap[pos]][h] : 0, for pos < mpad
__global__ void transpose_gather(const float* __restrict__ mv, const int* __restrict__ posmap,
                                 const int* __restrict__ smalls, bf16_t* __restrict__ cVt) {
  __shared__ float tile[32][33];
  const int cnt = smalls[0], mpad = smalls[1];
  const int p0 = blockIdx.y * 32;
  if (p0 >= mpad) return;
  const int tx = threadIdx.x & 31, ty = threadIdx.x >> 5;  // 32 x 8
  const int h0 = blockIdx.x * 32;
  #pragma unroll
  for (int j = 0; j < 32; j += 8) {
    const int pos = p0 + ty + j;
    float val = 0.f;
    if (pos < cnt) val = mv[(size_t)posmap[pos] * 1024 + h0 + tx];
    tile[ty + j][tx] = val;
  }
  __syncthreads();
  #pragma unroll
  for (int j = 0; j < 32; j += 8)
    cVt[(size_t)(h0 + ty + j) * MSLOTS + p0 + tx] = (bf16_t)tile[tx][ty + j];
}

__global__ void zero_f32(float* __restrict__ p, int n4) {
  int i = blockIdx.x * blockDim.x + threadIdx.x;
  if (i < n4) ((float4*)p)[i] = (float4){0.f, 0.f, 0.f, 0.f};
}

// out = retrf * (1/den[row]) -> bf16 (atomic split-K mode)
__global__ void scale_cvt(const float* __restrict__ retrf, const float* __restrict__ den,
                          bf16_t* __restrict__ out, int n4) {
  int i = blockIdx.x * blockDim.x + threadIdx.x;
  if (i >= n4) return;
  float4 s = ((const float4*)retrf)[i];
  const int row = (i * 4) >> 10;  // HDIM=1024
  const float r = 1.0f / den[row];
  bf16x4 o;
  o[0] = (bf16_t)(s.x * r); o[1] = (bf16_t)(s.y * r);
  o[2] = (bf16_t)(s.z * r); o[3] = (bf16_t)(s.w * r);
  ((bf16x4*)out)[i] = o;
}

// sum ks fp32 partial slabs, scale by 1/den[row], store bf16 (partial split-K mode)
__global__ void reduce_scale(const float* __restrict__ part, size_t partStride, int ks,
                             const float* __restrict__ den, bf16_t* __restrict__ out, int n4) {
  int i = blockIdx.x * blockDim.x + threadIdx.x;
  if (i >= n4) return;
  float4 s = ((const float4*)part)[i];
  for (int k = 1; k < ks; ++k) {
    float4 t = ((const float4*)(part + (size_t)k * partStride))[i];
    s.x += t.x; s.y += t.y; s.z += t.z; s.w += t.w;
  }
  const int row = (i * 4) >> 10;  // HDIM=1024
  const float r = 1.0f / den[row];
  bf16x4 o;
  o[0] = (bf16_t)(s.x * r); o[1] = (bf16_t)(s.y * r);
  o[2] = (bf16_t)(s.z * r); o[3] = (bf16_t)(s.w * r);
  ((bf16x4*)out)[i] = o;
}

// ---------------------------------------------------------------------------
// 8-phase-style 256x256 GEMM, BK=64, double-buffered LDS (128 KiB), 8 waves
// (512 thr). C = A * Bt^T; A:[rows,ldk], Bt:[N,ldk] row-major.
//
// Wave decomposition (interleaved M-split so phase q consumes one 64-row
// A-slab): wave wr=wave>>2 (0,1), wc=wave&3. Phase q (q=0..3) computes output
// rows q*64 + wr*32 + {0,16} x cols wc*64..+63 over the full K=64 tile
// (16 MFMA). So A is consumed slab-by-slab: phase 0,1 -> A half0 (rows 0-127),
// phase 2,3 -> A half1. All waves read their B rows (wave-fixed) at phase 0.
//
// Stage schedule (per K-tile t, staging tile t+1, one half-tile per phase,
// 2 glds/thread each): B0@p0, B1@p1, A0@p2, A1@p3.
// FIFO-derived waits (per-wave vmcnt units = glds instructions):
//   p0: vmcnt(2)  -> B0,B1,A0 of tile t landed; A1(t) still in flight
//   p1: none      (A rows 64-127 already landed)
//   p2: vmcnt(4)  -> A1(t) landed; B0,B1 of t+1 in flight
//   p3: none
// Last tile: p2 waits vmcnt(0). 6-8 loads stay in flight across every barrier
// (T4); one uniform s_barrier per phase; sched_barrier(0) pins stage/read/MFMA
// ordering; setprio(1) wraps each MFMA cluster (T5).
//
// T2 swizzle: LDS dest stays linear (required by global_load_lds); the GLOBAL
// source 16B-slot is pre-swizzled slot^ (row&7) and ds_read applies the same
// involution -> b128 reads spread across banks (was 8-way conflict).
//
// EPI 1: outb = cmask[col] ? exp(10*acc) : 0 (bf16) + atomic row-sums into den
// EPI 3: split-K over K=mpad: atomicAdd(outf, acc)
// EPI 4: split-K over K=mpad: outf[z-slab] = acc
#define SB __builtin_amdgcn_sched_barrier(0)

#define STAGE(TT, HF)                                                          \
  {                                                                            \
    const int isB_ = ((HF) < 2) ? 1 : 0;                                       \
    const int h_ = (HF) & 1;                                                   \
    bf16_t* d_ = &sm[(TT) & 1][isB_][h_ * 8192 + tid * 8];                     \
    const bf16_t* s_ = (isB_ ? pBstg : pAstg) + (size_t)h_ * 128 * ldk +       \
                       (size_t)(kstart + ((TT) << 6));                         \
    load16_lds(s_, d_);                                                        \
    load16_lds(s_ + (size_t)64 * ldk, d_ + 4096);                              \
  }

#define RDA(Q)                                                                 \
  {                                                                            \
    _Pragma("unroll") for (int m2 = 0; m2 < 2; ++m2)                           \
      _Pragma("unroll") for (int kk = 0; kk < 2; ++kk) {                       \
        const int r_ = (Q) * 64 + wr * 32 + m2 * 16 + lr;                      \
        const int sg_ = kk * 4 + lq;                                           \
        af[m2 * 2 + kk] =                                                      \
            *(const bf16x8*)(bA + r_ * 128 + ((sg_ ^ (r_ & 7)) << 4));         \
      }                                                                        \
  }

#define RDB()                                                                  \
  {                                                                            \
    _Pragma("unroll") for (int n = 0; n < 4; ++n)                              \
      _Pragma("unroll") for (int kk = 0; kk < 2; ++kk) {                       \
        const int r_ = wc * 64 + n * 16 + lr;                                  \
        const int sg_ = kk * 4 + lq;                                           \
        bfr[n * 2 + kk] =                                                      \
            *(const bf16x8*)(bB + r_ * 128 + ((sg_ ^ (r_ & 7)) << 4));         \
      }                                                                        \
  }

#define MFQ(Q)                                                                 \
  {                                                                            \
    _Pragma("unroll") for (int m2 = 0; m2 < 2; ++m2)                           \
      _Pragma("unroll") for (int n = 0; n < 4; ++n)                            \
        _Pragma("unroll") for (int kk = 0; kk < 2; ++kk)                       \
          acc[(Q) * 2 + m2][n] = __builtin_amdgcn_mfma_f32_16x16x32_bf16(      \
              af[m2 * 2 + kk], bfr[n * 2 + kk], acc[(Q) * 2 + m2][n], 0, 0, 0);\
  }

template <int EPI>
__global__ __launch_bounds__(512, 2)
void gemm256(const bf16_t* __restrict__ A, const bf16_t* __restrict__ Bt,
             int ldk, int kLenIn, int ldc,
             const int* __restrict__ cmask,
             float* __restrict__ den,
             float* __restrict__ outf, bf16_t* __restrict__ outb,
             const int* __restrict__ smalls, int ks, size_t partStride) {
  __shared__ bf16_t sm[2][2][256 * 64];  // [buf][0=A 1=B] : 128 KiB
  const int tid = threadIdx.x;
  const int lane = tid & 63;
  const int wave = tid >> 6;
  const int wr = wave >> 2;  // 0..1
  const int wc = wave & 3;   // 0..3
  const int lr = lane & 15;
  const int lq = lane >> 4;

  int bx = blockIdx.x, by = blockIdx.y, bz = blockIdx.z;
  {
    const unsigned nx = gridDim.x, ny = gridDim.y;
    if ((ny & 7u) == 0u) {  // XCD-aware y-inner swizzle (bijective: exact /8)
      unsigned lin = blockIdx.x + nx * (blockIdx.y + ny * blockIdx.z);
      unsigned ylow = lin & 7u;
      lin >>= 3;
      const unsigned nyh = ny >> 3;
      unsigned yhigh = lin % nyh;
      lin /= nyh;
      bx = lin % nx;
      bz = lin / nx;
      by = ylow + 8u * yhigh;
    }
  }

  int kLen = kLenIn;
  int kstart = 0;
  if (EPI == 1) {
    if (bx * 256 >= smalls[1]) return;  // compacted N bound (block-uniform)
  }
  if (EPI == 3 || EPI == 4) {
    kLen = smalls[1] / ks;  // mpad % 512 == 0, ks in {4,8} -> kLen % 64 == 0
    kstart = bz * kLen;
  }
  const int nt = kLen >> 6;  // BK=64 tiles
  if (nt <= 0) return;       // uniform

  // Stage source addressing (pre-swizzled): thread handles 16B-chunks tid and
  // tid+512 of each 128-row half; chunk c -> row c>>3, slot c&7; global col16 =
  // slot ^ (row&7); LDS dest linear at chunk*16B.
  const size_t stgOff = (size_t)(tid >> 3) * ldk + (((tid & 7) ^ ((tid >> 3) & 7)) << 3);
  const bf16_t* pAstg = A + (size_t)(by * 256) * ldk + stgOff;
  const bf16_t* pBstg = Bt + (size_t)(bx * 256) * ldk + stgOff;

  f32x4 acc[8][4];
  #pragma unroll
  for (int m = 0; m < 8; ++m)
    #pragma unroll
    for (int n = 0; n < 4; ++n) acc[m][n] = (f32x4){0.f, 0.f, 0.f, 0.f};

  bf16x8 af[4], bfr[8];

  // prologue: stage all 4 halves of tile 0 (8 glds/wave in flight)
  STAGE(0, 0); STAGE(0, 1); STAGE(0, 2); STAGE(0, 3);

  for (int t = 0; t < nt; ++t) {
    const char* bA = (const char*)sm[t & 1][0];
    const char* bB = (const char*)sm[t & 1][1];
    const bool more = (t + 1 < nt);

    // ---- phase 0: needs B0,B1,A0 of tile t ----
    asm volatile("s_waitcnt vmcnt(2)" ::: "memory");
    SB; __builtin_amdgcn_s_barrier(); SB;
    if (more) STAGE(t + 1, 0);  // B0(t+1)
    RDB();
    RDA(0);
    __builtin_amdgcn_s_setprio(1); MFQ(0); __builtin_amdgcn_s_setprio(0); SB;

    // ---- phase 1: A rows 64-127 (already landed) ----
    __builtin_amdgcn_s_barrier(); SB;
    if (more) STAGE(t + 1, 1);  // B1(t+1)
    RDA(1);
    __builtin_amdgcn_s_setprio(1); MFQ(1); __builtin_amdgcn_s_setprio(0); SB;

    // ---- phase 2: needs A1 of tile t ----
    if (more) { asm volatile("s_waitcnt vmcnt(4)" ::: "memory"); }
    else      { asm volatile("s_waitcnt vmcnt(0)" ::: "memory"); }
    SB; __builtin_amdgcn_s_barrier(); SB;
    if (more) STAGE(t + 1, 2);  // A0(t+1)
    RDA(2);
    __builtin_amdgcn_s_setprio(1); MFQ(2); __builtin_amdgcn_s_setprio(0); SB;

    // ---- phase 3: A rows 192-255 (already landed) ----
    __builtin_amdgcn_s_barrier(); SB;
    if (more) STAGE(t + 1, 3);  // A1(t+1)
    RDA(3);
    __builtin_amdgcn_s_setprio(1); MFQ(3); __builtin_amdgcn_s_setprio(0); SB;
  }

  // C/D layout (m89-verified): col = lane&15, row = (lane>>4)*4 + r
  // frag (m=q*2+m2, n): row = by*256 + q*64 + wr*32 + m2*16 + lq*4 + r,
  //                     col = bx*256 + wc*64 + n*16 + lr
  const int colBase = bx * 256 + wc * 64 + lr;

  if (EPI == 1) {
    bool ok[4];
    #pragma unroll
    for (int n = 0; n < 4; ++n) ok[n] = cmask[colBase + n * 16] > 0;
    #pragma unroll
    for (int m = 0; m < 8; ++m) {
      const int row0 = by * 256 + (m >> 1) * 64 + wr * 32 + (m & 1) * 16 + lq * 4;
      #pragma unroll
      for (int r = 0; r < 4; ++r) {
        const int row = row0 + r;
        float s = 0.f;
        #pragma unroll
        for (int n = 0; n < 4; ++n) {
          float e = ok[n] ? exp2f(acc[m][n][r] * 14.426950408889634f) : 0.f;
          s += e;
          outb[(size_t)row * ldc + colBase + n * 16] = (bf16_t)e;
        }
        // reduce over the 16-lane col group, one atomic per row per wave
        s += __shfl_xor(s, 1);
        s += __shfl_xor(s, 2);
        s += __shfl_xor(s, 4);
        s += __shfl_xor(s, 8);
        if (lr == 0) atomicAdd(&den[row], s);
      }
    }
  }
  if (EPI == 3 || EPI == 4) {
    if (EPI == 4) outf += (size_t)bz * partStride;
    #pragma unroll
    for (int m = 0; m < 8; ++m) {
      const int row0 = by * 256 + (m >> 1) * 64 + wr * 32 + (m & 1) * 16 + lq * 4;
      #pragma unroll
      for (int n = 0; n < 4; ++n)
        #pragma unroll
        for (int r = 0; r < 4; ++r) {
          const size_t idx = (size_t)(row0 + r) * ldc + colBase + n * 16;
          if (EPI == 3) atomicAdd(&outf[idx], acc[m][n][r]);
          else outf[idx] = acc[m][n][r];
        }
    }
  }
}

// m97-style 128x128 bf16 GEMM (kept for the two HxH projections: 512 blocks
// fill all 256 CUs, operands L2-resident). C = A * Bt^T + bias.
__global__ void gemm_bt(const bf16_t* __restrict__ A, const bf16_t* __restrict__ Bt,
                        int ldk, int kLenIn, int ldc,
                        const float* __restrict__ bias,
                        float* __restrict__ outf) {
  __shared__ bf16_t lA[128 * 32];
  __shared__ bf16_t lB[128 * 32];
  const int t = threadIdx.x;
  const int lane = t & 63;
  const int wave = t >> 6;
  const int wm = (wave >> 1) << 6;
  const int wn = (wave & 1) << 6;
  const int lr = lane & 15;
  const int lq = lane >> 4;

  int bx = blockIdx.x, by = blockIdx.y;
  {
    const unsigned nx = gridDim.x, ny = gridDim.y;
    if ((ny & 7u) == 0u) {
      unsigned lin = blockIdx.x + nx * blockIdx.y;
      unsigned ylow = lin & 7u;
      lin >>= 3;
      const unsigned nyh = ny >> 3;
      unsigned yhigh = lin % nyh;
      lin /= nyh;
      bx = lin % nx;
      by = ylow + 8u * yhigh;
    }
  }

  const int kLen = kLenIn;
  const int r0 = t >> 2;
  const int c0 = (t & 3) * 8;
  const bf16_t* pA0 = A + (size_t)(by * 128 + r0) * ldk + c0;
  const bf16_t* pA1 = pA0 + (size_t)64 * ldk;
  const bf16_t* pB0 = Bt + (size_t)(bx * 128 + r0) * ldk + c0;
  const bf16_t* pB1 = pB0 + (size_t)64 * ldk;

  f32x4 acc[4][4];
  #pragma unroll
  for (int i = 0; i < 4; ++i)
    #pragma unroll
    for (int j = 0; j < 4; ++j) acc[i][j] = (f32x4){0.f, 0.f, 0.f, 0.f};

  for (int k0 = 0; k0 < kLen; k0 += 32) {
    __syncthreads();
    load16_lds(pA0, &lA[t * 8]);
    load16_lds(pA1, &lA[2048 + t * 8]);
    load16_lds(pB0, &lB[t * 8]);
    load16_lds(pB1, &lB[2048 + t * 8]);
    pA0 += 32; pA1 += 32; pB0 += 32; pB1 += 32;
    __syncthreads();
    bf16x8 af[4], bfv[4];
    #pragma unroll
    for (int i = 0; i < 4; ++i)
      af[i] = *(const bf16x8*)&lA[(wm + i * 16 + lr) * 32 + lq * 8];
    #pragma unroll
    for (int j = 0; j < 4; ++j)
      bfv[j] = *(const bf16x8*)&lB[(wn + j * 16 + lr) * 32 + lq * 8];
    #pragma unroll
    for (int i = 0; i < 4; ++i)
      #pragma unroll
      for (int j = 0; j < 4; ++j)
        acc[i][j] = __builtin_amdgcn_mfma_f32_16x16x32_bf16(af[i], bfv[j], acc[i][j], 0, 0, 0);
  }

  const int colBase = bx * 128 + wn + lr;
  const int rowBase = by * 128 + wm + lq * 4;

  #pragma unroll
  for (int j = 0; j < 4; ++j) {
    const int col = colBase + j * 16;
    const float bval = bias[col];
    #pragma unroll
    for (int i = 0; i < 4; ++i) {
      const int row = rowBase + i * 16;
      #pragma unroll
      for (int r = 0; r < 4; ++r)
        outf[(size_t)(row + r) * ldc + col] = acc[i][j][r] + bval;
    }
  }
}

extern "C" void kernel_launch(void* const* d_in, const int* in_sizes, int n_in,
                              void* d_out, int out_size, void* d_ws, size_t ws_size,
                              hipStream_t stream) {
  const float* hs = (const float*)d_in[0];
  const float* Wk = (const float*)d_in[1];
  const float* bk = (const float*)d_in[2];
  // d_in[3]=Wv, d_in[4]=bv are unused by the reference
  const float* Wo = (const float*)d_in[5];
  const float* bo = (const float*)d_in[6];
  const float* mk = (const float*)d_in[7];
  const float* mv = (const float*)d_in[8];
  const int* usage = (const int*)d_in[9];
  float* out = (float*)d_out;

  char* ws = (char*)d_ws;
  size_t off = 0;
  auto alloc = [&](size_t b) -> void* {
    void* p = ws + off;
    off += (b + 255) & ~(size_t)255;
    return p;
  };
  // Persistent buffers (live across the chunk loop)
  bf16_t* cmkn = (bf16_t*)alloc((size_t)MSLOTS * HDIM * 2);
  bf16_t* cVt = (bf16_t*)alloc((size_t)HDIM * MSLOTS * 2);
  bf16_t* qnb = (bf16_t*)alloc((size_t)NROWS * HDIM * 2);
  bf16_t* retrb = (bf16_t*)alloc((size_t)NROWS * HDIM * 2);
  bf16_t* Wob = (bf16_t*)alloc((size_t)HDIM * HDIM * 2);
  float* den = (float*)alloc((size_t)NROWS * 4);
  int* posmap = (int*)alloc((size_t)MSLOTS * 4);
  int* cmask = (int*)alloc((size_t)MSLOTS * 4);
  int* smalls = (int*)alloc(256 * 4);
  const size_t fixed = off;

  // Overlay region: phase A = [hsb][Wkb][qf] (dead after stage 1);
  // loop = [P chunk][retrf or partial slabs]. Prefer partial-slab split-K,
  // fall back to atomic accumulate when ws is tight. ks in {4,8} only
  // (kLen must stay a multiple of 64 for BK=64).
  int chunk = 256, ksplit = 4, partialMode = 0;
  {
    const int cc[8] = {4096, 4096, 2048, 2048, 1024, 1024, 512, 256};
    const int kk[8] = {4, 4, 8, 8, 8, 8, 8, 4};
    const int pp[8] = {1, 0, 1, 0, 1, 0, 0, 0};
    for (int ci = 0; ci < 8; ++ci) {
      size_t outBytes = pp[ci] ? (size_t)cc[ci] * HDIM * 4 * kk[ci] : (size_t)cc[ci] * HDIM * 4;
      size_t region = (size_t)cc[ci] * MSLOTS * 2 + outBytes;
      size_t phaseA = (size_t)NROWS * HDIM * 2 + (size_t)HDIM * HDIM * 2 +
                      (size_t)NROWS * HDIM * 4 + 1024;
      if (region < phaseA) region = phaseA;
      if (fixed + region <= ws_size) {
        chunk = cc[ci]; ksplit = kk[ci]; partialMode = pp[ci];
        break;
      }
    }
  }
  bf16_t* hsb = (bf16_t*)(ws + fixed);
  bf16_t* Wkb = (bf16_t*)(ws + fixed + (size_t)NROWS * HDIM * 2);
  float* qf = (float*)(ws + fixed + (size_t)NROWS * HDIM * 2 + (size_t)HDIM * HDIM * 2);
  bf16_t* P = (bf16_t*)(ws + fixed);
  float* retrf = (float*)(ws + fixed + (size_t)chunk * MSLOTS * 2);  // or slab base
  const size_t partStride = (size_t)chunk * HDIM;

  // ---- stage 0: compaction + dtype prep ----
  init_compact<<<MSLOTS / 256, 256, 0, stream>>>(cmask);
  compact_scan<<<1, 1024, 0, stream>>>(usage, posmap, cmask, smalls);
  cvt_f32_bf16<<<(NROWS * HDIM / 8 + 255) / 256, 256, 0, stream>>>(hs, hsb, NROWS * HDIM / 8);
  cvt_f32_bf16<<<(HDIM * HDIM / 8 + 255) / 256, 256, 0, stream>>>(Wk, Wkb, HDIM * HDIM / 8);
  cvt_f32_bf16<<<(HDIM * HDIM / 8 + 255) / 256, 256, 0, stream>>>(Wo, Wob, HDIM * HDIM / 8);
  normalize_gather<<<MSLOTS, 256, 0, stream>>>(mk, posmap, smalls, cmkn);
  transpose_gather<<<dim3(HDIM / 32, MSLOTS / 32), 256, 0, stream>>>(mv, posmap, smalls, cVt);

  // ---- stage 1: q = hs @ Wk^T + bk (fp32), then normalize -> qn bf16 ----
  gemm_bt<<<dim3(HDIM / 128, NROWS / 128), 256, 0, stream>>>(
      hsb, Wkb, HDIM, HDIM, HDIM, bk, qf);
  normalize_rows<<<NROWS, 256, 0, stream>>>(qf, qnb);

  // ---- stage 2/3: P = exp(10 * qn@cmkn^T) masked (+row sums); retr = P@V / den ----
  for (int c = 0; c < NROWS; c += chunk) {
    zero_f32<<<(chunk / 4 + 255) / 256, 256, 0, stream>>>(den, chunk / 4);
    gemm256<1><<<dim3(MSLOTS / 256, chunk / 256), 512, 0, stream>>>(
        qnb + (size_t)c * HDIM, cmkn, HDIM, HDIM, MSLOTS, cmask, den, nullptr, P,
        smalls, 1, 0);
    if (partialMode) {
      gemm256<4><<<dim3(HDIM / 256, chunk / 256, ksplit), 512, 0, stream>>>(
          P, cVt, MSLOTS, 0, HDIM, nullptr, nullptr, retrf, nullptr, smalls, ksplit,
          partStride);
      reduce_scale<<<(chunk * HDIM / 4 + 255) / 256, 256, 0, stream>>>(
          retrf, partStride, ksplit, den, retrb + (size_t)c * HDIM, chunk * HDIM / 4);
    } else {
      zero_f32<<<(chunk * HDIM / 4 + 255) / 256, 256, 0, stream>>>(retrf, chunk * HDIM / 4);
      gemm256<3><<<dim3(HDIM / 256, chunk / 256, ksplit), 512, 0, stream>>>(
          P, cVt, MSLOTS, 0, HDIM, nullptr, nullptr, retrf, nullptr, smalls, ksplit,
          0);
      scale_cvt<<<(chunk * HDIM / 4 + 255) / 256, 256, 0, stream>>>(
          retrf, den, retrb + (size_t)c * HDIM, chunk * HDIM / 4);
    }
  }

  // ---- stage 4: out = retrieved @ Wo^T + bo (fp32) ----
  gemm_bt<<<dim3(HDIM / 128, NROWS / 128), 256, 0, stream>>>(
      retrb, Wob, HDIM, HDIM, HDIM, bo, out);
}